// Round 13
// baseline (842.670 us; speedup 1.0000x reference)
//
#include <hip/hip_runtime.h>
#include <hip/hip_bf16.h>
#include <hip/hip_fp16.h>

#define SEQ 8192
#define DM  1024   // d_in == d_out == 1024

typedef __attribute__((ext_vector_type(8))) short    bf16x8;
typedef __attribute__((ext_vector_type(8))) _Float16 f16x8;
typedef __attribute__((ext_vector_type(4))) float    f32x4;

union H8 { _Float16 h[8]; int4 v; };

__device__ __forceinline__ unsigned short f2bf(float f) {
    union { float f; unsigned u; } x; x.f = f;
    unsigned r = x.u + 0x7fffu + ((x.u >> 16) & 1u);
    return (unsigned short)(r >> 16);
}
__device__ __forceinline__ float bf2f(unsigned short h) {
    union { unsigned u; float f; } x; x.u = ((unsigned)h) << 16;
    return x.f;
}

// async global->LDS, 16B per lane; lds dest wave-uniform base (HW adds lane*16)
__device__ __forceinline__ void gld16(const unsigned short* g, unsigned short* l) {
    __builtin_amdgcn_global_load_lds(
        (const __attribute__((address_space(1))) void*)g,
        (__attribute__((address_space(3))) void*)l, 16, 0, 0);
}

// ------- merged prep: blocks [0,8192) split x; blocks [8192,8960) transpose+split W -------
__global__ __launch_bounds__(256) void prep_kernel(const float* __restrict__ x,
    unsigned short* __restrict__ xhi, unsigned short* __restrict__ xlo,
    const float* W0, const float* W1, const float* W2,
    unsigned short* H0, unsigned short* L0,
    unsigned short* H1, unsigned short* L1,
    unsigned short* H2, unsigned short* L2)
{
    __shared__ float tile[64][65];
    int t = threadIdx.x;

    if (blockIdx.x < 8192) {
        // ---- split x (fp32 -> bf16 hi/lo), 1024 elems per block ----
        int base = (blockIdx.x * 256 + t) * 4;
        float4 v = *(const float4*)(x + base);
        float f[4] = {v.x, v.y, v.z, v.w};
        unsigned short h[4], l[4];
#pragma unroll
        for (int j = 0; j < 4; j++) { h[j] = f2bf(f[j]); l[j] = f2bf(f[j] - bf2f(h[j])); }
        ushort4 hv = {h[0], h[1], h[2], h[3]};
        ushort4 lv = {l[0], l[1], l[2], l[3]};
        *(ushort4*)(xhi + base) = hv;
        *(ushort4*)(xlo + base) = lv;
        return;
    }

    // ---- transpose + split W [1024k x 1024n] -> Wt hi/lo [n][k] ----
    int id = blockIdx.x - 8192;          // 0..767
    int z  = id >> 8;                    // which W
    int rem = id & 255;
    int bn = (rem & 15) * 64;
    int bk = (rem >> 4) * 64;
    const float* W = (z == 0) ? W0 : (z == 1) ? W1 : W2;
    unsigned short* Wthi = (z == 0) ? H0 : (z == 1) ? H1 : H2;
    unsigned short* Wtlo = (z == 0) ? L0 : (z == 1) ? L1 : L2;

#pragma unroll
    for (int p = 0; p < 4; p++) {
        int r = p * 16 + (t >> 4);
        int c = (t & 15) * 4;
        float4 v = *(const float4*)(W + (size_t)(bk + r) * DM + bn + c);
        tile[r][c] = v.x; tile[r][c+1] = v.y; tile[r][c+2] = v.z; tile[r][c+3] = v.w;
    }
    __syncthreads();
#pragma unroll
    for (int p = 0; p < 2; p++) {
        int task = p * 256 + t;
        int rn = task >> 3;
        int kc = (task & 7) * 8;
        union { unsigned short u[8]; int4 v; } hh, ll;
#pragma unroll
        for (int j = 0; j < 8; j++) {
            float f = tile[kc + j][rn];
            hh.u[j] = f2bf(f);
            ll.u[j] = f2bf(f - bf2f(hh.u[j]));
        }
        size_t o = (size_t)(bn + rn) * DM + bk + kc;
        *(int4*)(Wthi + o) = hh.v;
        *(int4*)(Wtlo + o) = ll.v;
    }
}

// ============ 128x128-tile GEMM, 256 threads (4 waves, 64x64 each), BK=32 ============
// A:[M x KD], B:[N x KD] row-major (contraction contiguous), ushort elements.
// Grid mapping: MODE 2 uses (x=n-tile, y=m-tile); all others use (x=m-tile, y=n-tile)
// so that XCD = flat_id%8 = row-tile%8 -> the d-tiles sharing an A-slice co-reside
// on one XCD and share its L2 (cuts E re-reads from L3 ~4x in PV).
// MODE 0: split bf16 -> split bf16 out; blockIdx.z=0 -> (B_,Blo_,Chi_,Clo_), z=1 -> (B2,...)
// MODE 1: plain bf16 -> f16 out row-major (V projection), KD=1024
// MODE 2: split bf16 -> scores epilogue: E=f16(exp(s-max64)), T=max, Z=sumexp, KD=1024
// MODE 3: f16 PV with Sc folded into the A-fragment (Sct[tile64][row], transposed), f32 out
template<int MODE, int KD>
__global__ __launch_bounds__(256) void gemm128(
    const unsigned short* A,   const unsigned short* Alo,
    const unsigned short* B_,  const unsigned short* Blo_,
    const unsigned short* B2,  const unsigned short* B2lo,
    unsigned short* Chi_, unsigned short* Clo_,
    unsigned short* Chi2, unsigned short* Clo2,
    _Float16* Cf16, float* Cf32,
    _Float16* Eo, float* Tt, float* Zt, const float* Sct)
{
    constexpr bool SPLIT = (MODE == 0 || MODE == 2);
    __shared__ alignas(16) unsigned short sAhi[128 * 32];
    __shared__ alignas(16) unsigned short sBhi[128 * 32];
    __shared__ alignas(16) unsigned short sAlo[SPLIT ? 128 * 32 : 16];
    __shared__ alignas(16) unsigned short sBlo[SPLIT ? 128 * 32 : 16];

    const unsigned short* B   = B_;
    const unsigned short* Blo = Blo_;
    unsigned short* Chi = Chi_;
    unsigned short* Clo = Clo_;
    if (MODE == 0 && blockIdx.z == 1) { B = B2; Blo = B2lo; Chi = Chi2; Clo = Clo2; }

    const int m0 = (MODE == 2 ? blockIdx.y : blockIdx.x) * 128;
    const int n0 = (MODE == 2 ? blockIdx.x : blockIdx.y) * 128;
    const int t = threadIdx.x;
    const int wave = t >> 6, lane = t & 63;
    const int wr = wave >> 1, wc = wave & 1;    // wave quadrant (64x64)
    const int i16 = lane & 15, quad = lane >> 4;

    // staging: wave stages rows wave*32 .. wave*32+31 (two 16-row chunks)
    const int rs = wave * 32 + (lane >> 2);
    const int cs = (lane & 3) * 8;
    const size_t aoff = (size_t)(m0 + rs) * KD + cs;
    const size_t boff = (size_t)(n0 + rs) * KD + cs;
    const int ldsb = wave * 1024;   // element offset of this wave's staging region

    f32x4 acc[4][4] = {};
    float scf[4];                   // MODE 3: per-mt softmax scale for current 64-col k-tile

    for (int k = 0; k < KD; k += 32) {
        if constexpr (MODE == 3) {
            if ((k & 63) == 0) {
#pragma unroll
                for (int mt = 0; mt < 4; mt++)
                    scf[mt] = Sct[(size_t)(k >> 6) * SEQ + m0 + wr * 64 + mt * 16 + i16];
            }
        }
        __syncthreads();
        gld16(A + aoff + k,            sAhi + ldsb);
        gld16(A + aoff + 16 * KD + k,  sAhi + ldsb + 512);
        gld16(B + boff + k,            sBhi + ldsb);
        gld16(B + boff + 16 * KD + k,  sBhi + ldsb + 512);
        if constexpr (SPLIT) {
            gld16(Alo + aoff + k,           sAlo + ldsb);
            gld16(Alo + aoff + 16 * KD + k, sAlo + ldsb + 512);
            gld16(Blo + boff + k,           sBlo + ldsb);
            gld16(Blo + boff + 16 * KD + k, sBlo + ldsb + 512);
        }
        __syncthreads();

        bf16x8 ahi[4], alo[4];
        f16x8 af[4];
#pragma unroll
        for (int mt = 0; mt < 4; mt++) {
            int r = wr * 64 + mt * 16 + i16;
            ahi[mt] = *(const bf16x8*)(sAhi + r * 32 + quad * 8);
            if constexpr (SPLIT) alo[mt] = *(const bf16x8*)(sAlo + r * 32 + quad * 8);
            if constexpr (MODE == 3) {
                f16x8 av = __builtin_bit_cast(f16x8, ahi[mt]);
                _Float16 sh = (_Float16)scf[mt];
#pragma unroll
                for (int j = 0; j < 8; j++) av[j] *= sh;
                af[mt] = av;
            }
        }
#pragma unroll
        for (int nt = 0; nt < 4; nt++) {
            int r = wc * 64 + nt * 16 + i16;
            bf16x8 bhi = *(const bf16x8*)(sBhi + r * 32 + quad * 8);
            bf16x8 blo;
            if constexpr (SPLIT) blo = *(const bf16x8*)(sBlo + r * 32 + quad * 8);
#pragma unroll
            for (int mt = 0; mt < 4; mt++) {
                if constexpr (MODE == 3) {
                    acc[mt][nt] = __builtin_amdgcn_mfma_f32_16x16x32_f16(
                        af[mt], __builtin_bit_cast(f16x8, bhi), acc[mt][nt], 0, 0, 0);
                } else {
                    acc[mt][nt] = __builtin_amdgcn_mfma_f32_16x16x32_bf16(ahi[mt], bhi, acc[mt][nt], 0, 0, 0);
                    if constexpr (SPLIT) {
                        acc[mt][nt] = __builtin_amdgcn_mfma_f32_16x16x32_bf16(ahi[mt], blo, acc[mt][nt], 0, 0, 0);
                        acc[mt][nt] = __builtin_amdgcn_mfma_f32_16x16x32_bf16(alo[mt], bhi, acc[mt][nt], 0, 0, 0);
                    }
                }
            }
        }
    }

    // ---------------- epilogues ----------------
    if constexpr (MODE == 0) {
#pragma unroll
        for (int mt = 0; mt < 4; mt++)
#pragma unroll
            for (int nt = 0; nt < 4; nt++)
#pragma unroll
                for (int r = 0; r < 4; r++) {
                    int row = m0 + wr * 64 + mt * 16 + quad * 4 + r;
                    int col = n0 + wc * 64 + nt * 16 + i16;
                    float v = acc[mt][nt][r];
                    unsigned short h = f2bf(v);
                    Chi[(size_t)row * DM + col] = h;
                    Clo[(size_t)row * DM + col] = f2bf(v - bf2f(h));
                }
    } else if constexpr (MODE == 1) {
#pragma unroll
        for (int mt = 0; mt < 4; mt++)
#pragma unroll
            for (int nt = 0; nt < 4; nt++)
#pragma unroll
                for (int r = 0; r < 4; r++) {
                    int row = m0 + wr * 64 + mt * 16 + quad * 4 + r;
                    int col = n0 + wc * 64 + nt * 16 + i16;
                    Cf16[(size_t)row * DM + col] = (_Float16)acc[mt][nt][r];
                }
    } else if constexpr (MODE == 3) {
#pragma unroll
        for (int mt = 0; mt < 4; mt++)
#pragma unroll
            for (int nt = 0; nt < 4; nt++)
#pragma unroll
                for (int r = 0; r < 4; r++) {
                    int row = m0 + wr * 64 + mt * 16 + quad * 4 + r;
                    int col = n0 + wc * 64 + nt * 16 + i16;
                    Cf32[(size_t)row * DM + col] = acc[mt][nt][r];
                }
    } else {  // MODE 2: scores -> E = exp(s - tile64max), T (max), Z (sumexp), per 64-col tile
        const float scale = 0.03125f;  // 1/sqrt(1024)
        const int tix = (n0 + wc * 64) >> 6;   // 64-col tile index, 128 per row
#pragma unroll
        for (int mt = 0; mt < 4; mt++)
#pragma unroll
            for (int r = 0; r < 4; r++) {
                float s0 = acc[mt][0][r] * scale, s1 = acc[mt][1][r] * scale;
                float s2 = acc[mt][2][r] * scale, s3 = acc[mt][3][r] * scale;
                float mx = fmaxf(fmaxf(s0, s1), fmaxf(s2, s3));
                mx = fmaxf(mx, __shfl_xor(mx, 1));
                mx = fmaxf(mx, __shfl_xor(mx, 2));
                mx = fmaxf(mx, __shfl_xor(mx, 4));
                mx = fmaxf(mx, __shfl_xor(mx, 8));
                float e0 = __expf(s0 - mx), e1 = __expf(s1 - mx);
                float e2 = __expf(s2 - mx), e3 = __expf(s3 - mx);
                float z = e0 + e1 + e2 + e3;
                z += __shfl_xor(z, 1);
                z += __shfl_xor(z, 2);
                z += __shfl_xor(z, 4);
                z += __shfl_xor(z, 8);
                int row = m0 + wr * 64 + mt * 16 + quad * 4 + r;
                if (i16 == 0) {
                    Tt[(size_t)row * 128 + tix] = mx;
                    Zt[(size_t)row * 128 + tix] = z;
                }
                size_t eb = (size_t)row * SEQ + n0 + wc * 64 + i16;
                Eo[eb +  0] = (_Float16)e0;
                Eo[eb + 16] = (_Float16)e1;
                Eo[eb + 32] = (_Float16)e2;
                Eo[eb + 48] = (_Float16)e3;
            }
    }
}

// ---------------- transpose V [8192 x 1024] f16 -> Vt [1024 x 8192] ----------------
__global__ __launch_bounds__(256) void transpose_f16(const _Float16* __restrict__ in,
                                                     _Float16* __restrict__ out)
{
    __shared__ _Float16 tile[64][72];
    int bn = blockIdx.x * 64;
    int bm = blockIdx.y * 64;
    int t = threadIdx.x;
    int r = t >> 3, c = (t & 7) * 8;
#pragma unroll
    for (int p = 0; p < 2; p++) {
        int rr = p * 32 + r;
        H8 v; v.v = *(const int4*)(in + (size_t)(bm + rr) * DM + bn + c);
#pragma unroll
        for (int j = 0; j < 8; j++) tile[rr][c + j] = v.h[j];
    }
    __syncthreads();
#pragma unroll
    for (int p = 0; p < 2; p++) {
        int rr = p * 32 + r;
        H8 v;
#pragma unroll
        for (int j = 0; j < 8; j++) v.h[j] = tile[c + j][rr];
        *(int4*)(out + (size_t)(bn + rr) * SEQ + bm + c) = v.v;
    }
}

// ------- per-row softmax scale from per-tile stats, written TRANSPOSED -------
// Sct[t][r] = e^{T-m}/l, t in [0,128) 64-col tiles (tile-major so PV's gather is coalesced)
// one wave per row, 2 tiles per lane
__global__ __launch_bounds__(256) void sc_reduce(const float* __restrict__ Tt,
    const float* __restrict__ Zt, float* __restrict__ Sct)
{
    int row = blockIdx.x * 4 + (threadIdx.x >> 6);
    int lane = threadIdx.x & 63;
    size_t b = (size_t)row * 128 + lane;
    float t0 = Tt[b], t1 = Tt[b + 64];
    float z0 = Zt[b], z1 = Zt[b + 64];
    float m = fmaxf(t0, t1);
    for (int sh = 1; sh < 64; sh <<= 1) m = fmaxf(m, __shfl_xor(m, sh));
    float l = z0 * __expf(t0 - m) + z1 * __expf(t1 - m);
    for (int sh = 1; sh < 64; sh <<= 1) l += __shfl_xor(l, sh);
    float inv = 1.0f / l;
    Sct[(size_t)lane * SEQ + row]        = __expf(t0 - m) * inv;
    Sct[(size_t)(lane + 64) * SEQ + row] = __expf(t1 - m) * inv;
}

extern "C" void kernel_launch(void* const* d_in, const int* in_sizes, int n_in,
                              void* d_out, int out_size, void* d_ws, size_t ws_size,
                              hipStream_t stream)
{
    const float* x  = (const float*)d_in[0];
    const float* Wq = (const float*)d_in[1];
    const float* Wk = (const float*)d_in[2];
    const float* Wv = (const float*)d_in[3];
    float* Out = (float*)d_out;
    char* ws = (char*)d_ws;

    const size_t MB = 1024 * 1024;
    // Region [0, 128MB): first x-splits / W-splits / Vtmp, later E (after they are dead)
    unsigned short* xhi   = (unsigned short*)(ws + 0 * MB);
    unsigned short* xlo   = (unsigned short*)(ws + 16 * MB);
    unsigned short* Wqthi = (unsigned short*)(ws + 32 * MB);
    unsigned short* Wqtlo = (unsigned short*)(ws + 34 * MB);
    unsigned short* Wkthi = (unsigned short*)(ws + 36 * MB);
    unsigned short* Wktlo = (unsigned short*)(ws + 38 * MB);
    unsigned short* Wvthi = (unsigned short*)(ws + 40 * MB);
    unsigned short* Wvtlo = (unsigned short*)(ws + 42 * MB);
    _Float16*       Vtmp  = (_Float16*)     (ws + 44 * MB);   // dead after transpose
    _Float16*       E     = (_Float16*)     (ws + 0 * MB);    // 128 MB, written after splits dead

    size_t off = 128 * MB;
    unsigned short* Qhi = (unsigned short*)(ws + off); off += 16 * MB;
    unsigned short* Qlo = (unsigned short*)(ws + off); off += 16 * MB;
    unsigned short* Khi = (unsigned short*)(ws + off); off += 16 * MB;
    unsigned short* Klo = (unsigned short*)(ws + off); off += 16 * MB;
    _Float16*       Vt  = (_Float16*)      (ws + off); off += 16 * MB;
    float*          Tt  = (float*)         (ws + off); off += (size_t)SEQ * 128 * 4;
    float*          Zt  = (float*)         (ws + off); off += (size_t)SEQ * 128 * 4;
    float*          Sct = (float*)         (ws + off); off += (size_t)SEQ * 128 * 4;

    // 1. split x + transpose/split all 3 weights, one launch
    prep_kernel<<<8192 + 768, 256, 0, stream>>>(x, xhi, xlo, Wq, Wk, Wv,
        Wqthi, Wqtlo, Wkthi, Wktlo, Wvthi, Wvtlo);
    // 2. Q and K projections (one launch; x=row-tile so XCD shares x-rows)
    gemm128<0, DM><<<dim3(SEQ / 128, DM / 128, 2), 256, 0, stream>>>(
        xhi, xlo, Wqthi, Wqtlo, Wkthi, Wktlo,
        Qhi, Qlo, Khi, Klo, nullptr, nullptr, nullptr, nullptr, nullptr, nullptr);
    // 3. V projection (row-major out)
    gemm128<1, DM><<<dim3(SEQ / 128, DM / 128), 256, 0, stream>>>(
        xhi, nullptr, Wvthi, nullptr, nullptr, nullptr,
        nullptr, nullptr, nullptr, nullptr, (_Float16*)Vtmp, nullptr, nullptr, nullptr, nullptr, nullptr);
    // 4. transpose V
    transpose_f16<<<dim3(DM / 64, SEQ / 64), 256, 0, stream>>>(Vtmp, Vt);
    // 5. scores -> E (exp rel 64-col tile max), Tt, Zt
    gemm128<2, DM><<<dim3(SEQ / 128, SEQ / 128), 256, 0, stream>>>(
        Qhi, Qlo, Khi, Klo, nullptr, nullptr,
        nullptr, nullptr, nullptr, nullptr, nullptr, nullptr, E, Tt, Zt, nullptr);
    // 6. per-row/tile softmax scale -> Sct (transposed, per-64-col tile)
    sc_reduce<<<SEQ / 4, 256, 0, stream>>>(Tt, Zt, Sct);
    // 7. O = (E*Sct) @ V, scale folded into A-fragments; x=row-tile for XCD L2 sharing
    gemm128<3, SEQ><<<dim3(SEQ / 128, DM / 128), 256, 0, stream>>>(
        (const unsigned short*)E, nullptr, (const unsigned short*)Vt, nullptr, nullptr, nullptr,
        nullptr, nullptr, nullptr, nullptr, nullptr, Out, nullptr, nullptr, nullptr, Sct);
}